// Round 10
// baseline (397.459 us; speedup 1.0000x reference)
//
#include <hip/hip_runtime.h>
#include <hip/hip_bf16.h>
#include <math.h>

#define BB 4
#define TT 2048
#define DD 256
#define FF 1024
#define NL 4

typedef __bf16 bf16x8 __attribute__((ext_vector_type(8)));
typedef float f32x4 __attribute__((ext_vector_type(4)));

__device__ __forceinline__ void stage16(const __hip_bfloat16* gp, __hip_bfloat16* lp) {
  __builtin_amdgcn_global_load_lds(
      (const __attribute__((address_space(1))) unsigned int*)gp,
      (__attribute__((address_space(3))) unsigned int*)lp, 16, 0, 0);
}

// fast exact-GELU: 0.5x(1+erf(x/sqrt2)), erf via A&S 7.1.26 (|err|<1.5e-7)
__device__ __forceinline__ float gelu_f(float v) {
  float x = fabsf(v) * 0.70710678118654752f;
  float t = 1.0f / fmaf(0.3275911f, x, 1.0f);
  float p = t * fmaf(t, fmaf(t, fmaf(t, fmaf(t, 1.061405429f, -1.453152027f),
                                     1.421413741f), -0.284496736f), 0.254829592f);
  float erfv = copysignf(1.0f - p * __expf(-x * x), v);
  return 0.5f * v * (1.0f + erfv);
}

// ---------------- prologue: weight f32->bf16 (blocks 0..3071) + PE+LN0 (rest) ----
__global__ __launch_bounds__(256) void prologue_kernel(
    const float4* __restrict__ wq, const float4* __restrict__ wo,
    const float4* __restrict__ w1, const float4* __restrict__ w2,
    ushort4* __restrict__ dst,
    const float* __restrict__ tokens, const float* __restrict__ g,
    const float* __restrict__ b, float* __restrict__ x,
    __hip_bfloat16* __restrict__ sb) {
  if (blockIdx.x < 3072) {
    int gi = blockIdx.x * 256 + threadIdx.x;
    const float4* src;
    int off;
    if (gi < 196608)      { src = wq; off = gi; }
    else if (gi < 262144) { src = wo; off = gi - 196608; }
    else if (gi < 524288) { src = w1; off = gi - 262144; }
    else                  { src = w2; off = gi - 524288; }
    float4 v = src[off];
    ushort4 o;
    o.x = __hip_bfloat16_raw(__float2bfloat16(v.x)).x;
    o.y = __hip_bfloat16_raw(__float2bfloat16(v.y)).x;
    o.z = __hip_bfloat16_raw(__float2bfloat16(v.z)).x;
    o.w = __hip_bfloat16_raw(__float2bfloat16(v.w)).x;
    dst[gi] = o;
    return;
  }
  int row = (blockIdx.x - 3072) * 4 + (threadIdx.x >> 6);
  int lane = threadIdx.x & 63;
  int t = row & (TT - 1);
  const float* xr = tokens + (size_t)row * DD;
  float v[4];
  float s = 0.f;
#pragma unroll
  for (int i = 0; i < 4; ++i) {
    int d = lane + 64 * i;
    int i2 = d & ~1;
    float freq = expf((float)i2 * -(9.210340371976184f / 256.f));
    float ang = (float)t * freq;
    float pe = (d & 1) ? cosf(ang) : sinf(ang);
    v[i] = xr[d] + pe;
    s += v[i];
  }
#pragma unroll
  for (int off = 32; off; off >>= 1) s += __shfl_xor(s, off, 64);
  float mu = s * (1.f / DD);
  float vs = 0.f;
#pragma unroll
  for (int i = 0; i < 4; ++i) { float dd = v[i] - mu; vs = fmaf(dd, dd, vs); }
#pragma unroll
  for (int off = 32; off; off >>= 1) vs += __shfl_xor(vs, off, 64);
  float rr = rsqrtf(vs * (1.f / DD) + 1e-5f);
#pragma unroll
  for (int i = 0; i < 4; ++i) {
    int d = lane + 64 * i;
    x[(size_t)row * DD + d] = v[i];
    sb[(size_t)row * DD + d] = __float2bfloat16((v[i] - mu) * rr * g[d] + b[d]);
  }
}

// ---------------- bf16 MFMA GEMM, chunked LDS (layer-0 qkv only) ----------
template <int MW, int NW, int BK, int KTOT, int ACT>
__global__ __launch_bounds__(256) void mgemm_kernel(
    const __hip_bfloat16* __restrict__ A, const __hip_bfloat16* __restrict__ B,
    const float* __restrict__ bias, __hip_bfloat16* __restrict__ Cout,
    int M, int N) {
  constexpr int BM = 32 * MW, BN = 32 * NW, ROWS = BM + BN;
  constexpr int NCH = BK / 32;
  constexpr int CHB = ROWS * 32;
  constexpr int RG = ROWS / 16;
  constexpr int NST = NCH * RG;
  __shared__ __align__(16) __hip_bfloat16 sm[NCH * CHB];
  const int tid = threadIdx.x;
  const int wave = tid >> 6, lane = tid & 63;
  const int m0 = blockIdx.y * BM, n0 = blockIdx.x * BN;
  const int wm = (wave >> 1) * (16 * MW), wn = (wave & 1) * (16 * NW);
  const int quad = lane >> 4, lr = lane & 15;
  const int srow = lane >> 2, scol = (lane & 3) * 8;

  f32x4 acc[MW][NW] = {};

  for (int kt = 0; kt < KTOT; kt += BK) {
    __syncthreads();
#pragma unroll
    for (int i = 0; i < NST / 4; ++i) {
      int inst = i * 4 + wave;
      int c = inst / RG, grp = inst - c * RG;
      int r = grp * 16 + srow;
      const __hip_bfloat16* gp =
          (r < BM) ? (A + (size_t)(m0 + r) * KTOT + kt + c * 32 + scol)
                   : (B + (size_t)(n0 + (r - BM)) * KTOT + kt + c * 32 + scol);
      stage16(gp, sm + c * CHB + grp * 512);
    }
    __syncthreads();
#pragma unroll
    for (int c = 0; c < NCH; ++c) {
      bf16x8 af[MW], bfr[NW];
#pragma unroll
      for (int mi = 0; mi < MW; ++mi)
        af[mi] = *(const bf16x8*)(sm + c * CHB + (wm + mi * 16 + lr) * 32 + quad * 8);
#pragma unroll
      for (int ni = 0; ni < NW; ++ni)
        bfr[ni] = *(const bf16x8*)(sm + c * CHB + (BM + wn + ni * 16 + lr) * 32 + quad * 8);
#pragma unroll
      for (int mi = 0; mi < MW; ++mi)
#pragma unroll
        for (int ni = 0; ni < NW; ++ni)
          acc[mi][ni] = __builtin_amdgcn_mfma_f32_16x16x32_bf16(
              af[mi], bfr[ni], acc[mi][ni], 0, 0, 0);
    }
  }

#pragma unroll
  for (int mi = 0; mi < MW; ++mi) {
#pragma unroll
    for (int ni = 0; ni < NW; ++ni) {
      int col = n0 + wn + ni * 16 + lr;
      float bv = bias[col];
#pragma unroll
      for (int r = 0; r < 4; ++r) {
        int row = m0 + wm + mi * 16 + quad * 4 + r;
        float v = acc[mi][ni][r] + bv;
        if (ACT == 1) v = gelu_f(v);
        Cout[(size_t)row * N + col] = __float2bfloat16(v);
      }
    }
  }
}

// ---------------- bf16 GEMM, N=256 full-row, fused residual+LN (Wo path) ----
template <int KTOT, int FIN>
__global__ __launch_bounds__(256) void mgemm_ln_kernel(
    const __hip_bfloat16* __restrict__ A, const __hip_bfloat16* __restrict__ B,
    const float* __restrict__ bias, const float* __restrict__ res,
    const float* __restrict__ g, const float* __restrict__ bb,
    float* __restrict__ xout, void* __restrict__ yout) {
  constexpr int BM = 32, ROWS = BM + 256;
  constexpr int BK = 64, NCH = BK / 32;
  constexpr int CHB = ROWS * 32;
  constexpr int RG = ROWS / 16;
  constexpr int NST = NCH * RG;
  __shared__ __align__(16) __hip_bfloat16 sm[NCH * CHB];
  __shared__ float red1[4][BM], red2[4][BM];
  const int tid = threadIdx.x;
  const int wave = tid >> 6, lane = tid & 63;
  const int quad = lane >> 4, lr = lane & 15;
  const int m0 = blockIdx.x * BM;
  const int srow = lane >> 2, scol = (lane & 3) * 8;

  f32x4 acc[2][4] = {};

  for (int kt = 0; kt < KTOT; kt += BK) {
    __syncthreads();
#pragma unroll
    for (int i = 0; i < NST / 4; ++i) {
      int inst = i * 4 + wave;
      int c = inst / RG, grp = inst - c * RG;
      int r = grp * 16 + srow;
      const __hip_bfloat16* gp =
          (r < BM) ? (A + (size_t)(m0 + r) * KTOT + kt + c * 32 + scol)
                   : (B + (size_t)(r - BM) * KTOT + kt + c * 32 + scol);
      stage16(gp, sm + c * CHB + grp * 512);
    }
    __syncthreads();
#pragma unroll
    for (int c = 0; c < NCH; ++c) {
      bf16x8 af[2], bfr[4];
#pragma unroll
      for (int mi = 0; mi < 2; ++mi)
        af[mi] = *(const bf16x8*)(sm + c * CHB + (mi * 16 + lr) * 32 + quad * 8);
#pragma unroll
      for (int ni = 0; ni < 4; ++ni)
        bfr[ni] = *(const bf16x8*)(sm + c * CHB + (BM + wave * 64 + ni * 16 + lr) * 32 + quad * 8);
#pragma unroll
      for (int mi = 0; mi < 2; ++mi)
#pragma unroll
        for (int ni = 0; ni < 4; ++ni)
          acc[mi][ni] = __builtin_amdgcn_mfma_f32_16x16x32_bf16(
              af[mi], bfr[ni], acc[mi][ni], 0, 0, 0);
    }
  }

  float v[2][4][4];
  float s1[2][4] = {}, s2[2][4] = {};
#pragma unroll
  for (int mi = 0; mi < 2; ++mi)
#pragma unroll
    for (int ni = 0; ni < 4; ++ni) {
      int col = wave * 64 + ni * 16 + lr;
      float bv = bias[col];
#pragma unroll
      for (int r = 0; r < 4; ++r) {
        int row = m0 + mi * 16 + quad * 4 + r;
        float val = acc[mi][ni][r] + bv + res[(size_t)row * DD + col];
        v[mi][ni][r] = val;
        s1[mi][r] += val;
        s2[mi][r] = fmaf(val, val, s2[mi][r]);
      }
    }
#pragma unroll
  for (int mi = 0; mi < 2; ++mi)
#pragma unroll
    for (int r = 0; r < 4; ++r) {
#pragma unroll
      for (int off = 8; off; off >>= 1) {
        s1[mi][r] += __shfl_xor(s1[mi][r], off, 64);
        s2[mi][r] += __shfl_xor(s2[mi][r], off, 64);
      }
    }
  if (lr == 0) {
#pragma unroll
    for (int mi = 0; mi < 2; ++mi)
#pragma unroll
      for (int r = 0; r < 4; ++r) {
        red1[wave][mi * 16 + quad * 4 + r] = s1[mi][r];
        red2[wave][mi * 16 + quad * 4 + r] = s2[mi][r];
      }
  }
  __syncthreads();
#pragma unroll
  for (int mi = 0; mi < 2; ++mi)
#pragma unroll
    for (int r = 0; r < 4; ++r) {
      int rl = mi * 16 + quad * 4 + r;
      float ssum = red1[0][rl] + red1[1][rl] + red1[2][rl] + red1[3][rl];
      float qsum = red2[0][rl] + red2[1][rl] + red2[2][rl] + red2[3][rl];
      float mu = ssum * (1.f / DD);
      float var = qsum * (1.f / DD) - mu * mu;
      float rr = rsqrtf(var + 1e-5f);
      int row = m0 + rl;
#pragma unroll
      for (int ni = 0; ni < 4; ++ni) {
        int col = wave * 64 + ni * 16 + lr;
        float y = (v[mi][ni][r] - mu) * rr * g[col] + bb[col];
        if (FIN) {
          ((float*)yout)[(size_t)row * DD + col] = y;
        } else {
          ((__hip_bfloat16*)yout)[(size_t)row * DD + col] = __float2bfloat16(y);
          xout[(size_t)row * DD + col] = v[mi][ni][r];
        }
      }
    }
}

// ---------------- fused MLP (+ next-layer qkv) ----------------
// Block owns 32 rows (grid 256). A = sb (ln2-out) staged once; then per
// 128-col ff-chunk: h = gelu(A@W1^T+b1) -> hbuf (A-layout LDS) -> xacc +=
// h@W2chunk^T. Epilogue: v = xacc+b2+x -> LN -> (LAST: fp32 d_out) or
// (x write + sbuf2 -> qkv(l+1) GEMM -> big).  LDS 73.5 KB -> 2 blocks/CU.
template <int LAST>
__global__ __launch_bounds__(256) void mlp_kernel(
    const __hip_bfloat16* __restrict__ sb, const __hip_bfloat16* __restrict__ w1,
    const float* __restrict__ b1, const __hip_bfloat16* __restrict__ w2,
    const float* __restrict__ b2, const __hip_bfloat16* __restrict__ wq,
    const float* __restrict__ bq, const float* __restrict__ g,
    const float* __restrict__ bb, float* __restrict__ x,
    __hip_bfloat16* __restrict__ big, float* __restrict__ out) {
  __shared__ __align__(16) __hip_bfloat16 asbuf[8 * 1024];   // A (ln2-out) 32x256
  __shared__ __align__(16) __hip_bfloat16 sbuf2[8 * 1024];   // ln1(l+1) 32x256
  __shared__ __align__(16) __hip_bfloat16 hbuf[32 * 136];    // gelu-h 32x128
  __shared__ __align__(16) __hip_bfloat16 wstage[16384];     // 32 KB weight stage
  __shared__ float red1[4][32], red2[4][32];
  const int tid = threadIdx.x;
  const int wave = tid >> 6, lane = tid & 63;
  const int quad = lane >> 4, lr = lane & 15;
  const int srow = lane >> 2, scol = (lane & 3) * 8;
  const int t0 = blockIdx.x * 32;

  // stage A (sb rows t0..t0+31, all 256 k) into chunked layout [c][32r][32k]
#pragma unroll
  for (int i = 0; i < 4; ++i) {
    int inst = i * 4 + wave;               // 0..15
    int c = inst >> 1, grp = inst & 1;
    int r = grp * 16 + srow;
    stage16(sb + (size_t)(t0 + r) * 256 + c * 32 + scol,
            asbuf + c * 1024 + grp * 512);
  }
  __syncthreads();

  f32x4 xacc[2][4] = {};
  for (int fc = 0; fc < 8; ++fc) {
    const int ff0 = fc * 128;
    f32x4 hacc[2][2] = {};
#pragma unroll
    for (int kt2 = 0; kt2 < 2; ++kt2) {
      __syncthreads();                     // protect wstage + hbuf(prev fc)
#pragma unroll
      for (int i = 0; i < 8; ++i) {
        int inst = i * 4 + wave;           // 0..31
        int c2 = inst >> 3, grp = inst & 7;
        int r = grp * 16 + srow;
        stage16(w1 + (size_t)(ff0 + r) * 256 + kt2 * 128 + c2 * 32 + scol,
                wstage + c2 * 4096 + grp * 512);
      }
      __syncthreads();
#pragma unroll
      for (int c2 = 0; c2 < 4; ++c2) {
        bf16x8 af[2], bfr[2];
#pragma unroll
        for (int mi = 0; mi < 2; ++mi)
          af[mi] = *(const bf16x8*)(asbuf + (kt2 * 4 + c2) * 1024 + (mi * 16 + lr) * 32 + quad * 8);
#pragma unroll
        for (int ni = 0; ni < 2; ++ni)
          bfr[ni] = *(const bf16x8*)(wstage + c2 * 4096 + (wave * 2 + ni) * 512 + lr * 32 + quad * 8);
#pragma unroll
        for (int mi = 0; mi < 2; ++mi)
#pragma unroll
          for (int ni = 0; ni < 2; ++ni)
            hacc[mi][ni] = __builtin_amdgcn_mfma_f32_16x16x32_bf16(
                af[mi], bfr[ni], hacc[mi][ni], 0, 0, 0);
      }
    }
    // gelu -> hbuf (each wave writes its own 32-col strip, all 32 rows)
#pragma unroll
    for (int mi = 0; mi < 2; ++mi)
#pragma unroll
      for (int ni = 0; ni < 2; ++ni) {
        int col = wave * 32 + ni * 16 + lr;
        float bv = b1[ff0 + col];
#pragma unroll
        for (int r = 0; r < 4; ++r)
          hbuf[(mi * 16 + quad * 4 + r) * 136 + col] =
              __float2bfloat16(gelu_f(hacc[mi][ni][r] + bv));
      }
    __syncthreads();                       // hbuf ready (also W1 wstage reads done)
#pragma unroll
    for (int kt3 = 0; kt3 < 2; ++kt3) {
      if (kt3) __syncthreads();            // wstage reuse between kt3 iters
#pragma unroll
      for (int i = 0; i < 8; ++i) {
        int inst = i * 4 + wave;           // 0..31
        int c2 = inst >> 4, grp = inst & 15;
        int r = grp * 16 + srow;
        stage16(w2 + (size_t)r * 1024 + ff0 + kt3 * 64 + c2 * 32 + scol,
                wstage + c2 * 8192 + grp * 512);
      }
      __syncthreads();
#pragma unroll
      for (int c2 = 0; c2 < 2; ++c2) {
        bf16x8 af[2], bfr[4];
#pragma unroll
        for (int mi = 0; mi < 2; ++mi)
          af[mi] = *(const bf16x8*)(hbuf + (mi * 16 + lr) * 136 + kt3 * 64 + c2 * 32 + quad * 8);
#pragma unroll
        for (int ni = 0; ni < 4; ++ni)
          bfr[ni] = *(const bf16x8*)(wstage + c2 * 8192 + (wave * 4 + ni) * 512 + lr * 32 + quad * 8);
#pragma unroll
        for (int mi = 0; mi < 2; ++mi)
#pragma unroll
          for (int ni = 0; ni < 4; ++ni)
            xacc[mi][ni] = __builtin_amdgcn_mfma_f32_16x16x32_bf16(
                af[mi], bfr[ni], xacc[mi][ni], 0, 0, 0);
      }
    }
  }

  // epilogue: v = xacc + b2 + x; LN
  float v[2][4][4];
  float s1[2][4] = {}, s2[2][4] = {};
#pragma unroll
  for (int mi = 0; mi < 2; ++mi)
#pragma unroll
    for (int ni = 0; ni < 4; ++ni) {
      int col = wave * 64 + ni * 16 + lr;
      float bv = b2[col];
#pragma unroll
      for (int r = 0; r < 4; ++r) {
        int row = t0 + mi * 16 + quad * 4 + r;
        float val = xacc[mi][ni][r] + bv + x[(size_t)row * DD + col];
        v[mi][ni][r] = val;
        s1[mi][r] += val;
        s2[mi][r] = fmaf(val, val, s2[mi][r]);
      }
    }
#pragma unroll
  for (int mi = 0; mi < 2; ++mi)
#pragma unroll
    for (int r = 0; r < 4; ++r) {
#pragma unroll
      for (int off = 8; off; off >>= 1) {
        s1[mi][r] += __shfl_xor(s1[mi][r], off, 64);
        s2[mi][r] += __shfl_xor(s2[mi][r], off, 64);
      }
    }
  if (lr == 0) {
#pragma unroll
    for (int mi = 0; mi < 2; ++mi)
#pragma unroll
      for (int r = 0; r < 4; ++r) {
        red1[wave][mi * 16 + quad * 4 + r] = s1[mi][r];
        red2[wave][mi * 16 + quad * 4 + r] = s2[mi][r];
      }
  }
  __syncthreads();
#pragma unroll
  for (int mi = 0; mi < 2; ++mi)
#pragma unroll
    for (int r = 0; r < 4; ++r) {
      int rl = mi * 16 + quad * 4 + r;
      float ssum = red1[0][rl] + red1[1][rl] + red1[2][rl] + red1[3][rl];
      float qsum = red2[0][rl] + red2[1][rl] + red2[2][rl] + red2[3][rl];
      float mu = ssum * (1.f / DD);
      float var = qsum * (1.f / DD) - mu * mu;
      float rr = rsqrtf(var + 1e-5f);
      int row = t0 + rl;
#pragma unroll
      for (int ni = 0; ni < 4; ++ni) {
        int col = wave * 64 + ni * 16 + lr;
        float y = (v[mi][ni][r] - mu) * rr * g[col] + bb[col];
        if (LAST) {
          out[(size_t)row * DD + col] = y;
        } else {
          x[(size_t)row * DD + col] = v[mi][ni][r];
          sbuf2[(col >> 5) * 1024 + rl * 32 + (col & 31)] = __float2bfloat16(y);
        }
      }
    }

  if (!LAST) {
    __syncthreads();                       // sbuf2 ready
    for (int nc = 0; nc < 6; ++nc) {
      f32x4 qacc[2][2] = {};
#pragma unroll
      for (int kt2 = 0; kt2 < 2; ++kt2) {
        __syncthreads();                   // wstage reuse
#pragma unroll
        for (int i = 0; i < 8; ++i) {
          int inst = i * 4 + wave;
          int c2 = inst >> 3, grp = inst & 7;
          int r = grp * 16 + srow;
          stage16(wq + (size_t)(nc * 128 + r) * 256 + kt2 * 128 + c2 * 32 + scol,
                  wstage + c2 * 4096 + grp * 512);
        }
        __syncthreads();
#pragma unroll
        for (int c2 = 0; c2 < 4; ++c2) {
          bf16x8 af[2], bfr[2];
#pragma unroll
          for (int mi = 0; mi < 2; ++mi)
            af[mi] = *(const bf16x8*)(sbuf2 + (kt2 * 4 + c2) * 1024 + (mi * 16 + lr) * 32 + quad * 8);
#pragma unroll
          for (int ni = 0; ni < 2; ++ni)
            bfr[ni] = *(const bf16x8*)(wstage + c2 * 4096 + (wave * 2 + ni) * 512 + lr * 32 + quad * 8);
#pragma unroll
          for (int mi = 0; mi < 2; ++mi)
#pragma unroll
            for (int ni = 0; ni < 2; ++ni)
              qacc[mi][ni] = __builtin_amdgcn_mfma_f32_16x16x32_bf16(
                  af[mi], bfr[ni], qacc[mi][ni], 0, 0, 0);
        }
      }
#pragma unroll
      for (int mi = 0; mi < 2; ++mi)
#pragma unroll
        for (int ni = 0; ni < 2; ++ni) {
          int col = nc * 128 + wave * 32 + ni * 16 + lr;
          float bv = bq[col];
#pragma unroll
          for (int r = 0; r < 4; ++r) {
            int row = t0 + mi * 16 + quad * 4 + r;
            big[(size_t)row * 768 + col] = __float2bfloat16(qacc[mi][ni][r] + bv);
          }
        }
    }
  }
}

// ---------------- sliding-window attention, MFMA (R9, unchanged) ----------------
__global__ __launch_bounds__(256) void attn_kernel(const __hip_bfloat16* __restrict__ qkv,
                                                   __hip_bfloat16* __restrict__ o) {
  __shared__ __align__(16) __hip_bfloat16 KsPs[128 * 72];
  __shared__ __align__(16) __hip_bfloat16 Vt[64 * 136];
  const int bh = blockIdx.y;
  const int b = bh >> 2, h = bh & 3;
  const int t0 = blockIdx.x * 64;
  const int sbase = t0 - 63;
  const int tid = threadIdx.x;

  const __hip_bfloat16* kb = qkv + (size_t)(b * TT) * 768 + 256 + h * 64;
  const __hip_bfloat16* vb = kb + 256;
  union U8 { uint4 u; __hip_bfloat16 hx[8]; };
#pragma unroll
  for (int it = 0; it < 4; ++it) {
    int f = tid + it * 256;
    int si = f >> 3;
    int c8 = f & 7;
    int s = sbase + si;
    U8 kr, vr;
    kr.u = make_uint4(0, 0, 0, 0); vr.u = make_uint4(0, 0, 0, 0);
    if (s >= 0 && s < TT) {
      kr.u = *(const uint4*)&kb[(size_t)s * 768 + 8 * c8];
      vr.u = *(const uint4*)&vb[(size_t)s * 768 + 8 * c8];
    }
    *(uint4*)&KsPs[si * 72 + c8 * 8] = kr.u;
    int pc = (si >> 3) ^ c8;
#pragma unroll
    for (int j = 0; j < 8; ++j) Vt[(c8 * 8 + j) * 136 + pc * 8 + (si & 7)] = vr.hx[j];
  }
  __syncthreads();

  const int wave = tid >> 6, lane = tid & 63;
  const int quad = lane >> 4, lr = lane & 15;

  const __hip_bfloat16* qrow = qkv + (size_t)(b * TT + t0 + wave * 16 + lr) * 768 + h * 64;
  bf16x8 qa0 = *(const bf16x8*)(qrow + quad * 8);
  bf16x8 qa1 = *(const bf16x8*)(qrow + 32 + quad * 8);
  f32x4 sc[8];
#pragma unroll
  for (int c = 0; c < 8; ++c) {
    f32x4 a = {};
    bf16x8 kf0 = *(const bf16x8*)&KsPs[(c * 16 + lr) * 72 + quad * 8];
    a = __builtin_amdgcn_mfma_f32_16x16x32_bf16(qa0, kf0, a, 0, 0, 0);
    bf16x8 kf1 = *(const bf16x8*)&KsPs[(c * 16 + lr) * 72 + 32 + quad * 8];
    a = __builtin_amdgcn_mfma_f32_16x16x32_bf16(qa1, kf1, a, 0, 0, 0);
    sc[c] = a;
  }
  __syncthreads();

#pragma unroll
  for (int reg = 0; reg < 4; ++reg) {
    int dt = wave * 16 + quad * 4 + reg;
    float pv[8];
    float mx = -1e30f;
#pragma unroll
    for (int c = 0; c < 8; ++c) {
      int si = c * 16 + lr;
      float v = sc[c][reg] * 0.125f;
      bool ok = (si >= dt) && (si <= dt + 63) && (sbase + si >= 0);
      v = ok ? v : -1e30f;
      pv[c] = v;
      mx = fmaxf(mx, v);
    }
#pragma unroll
    for (int off = 8; off; off >>= 1) mx = fmaxf(mx, __shfl_xor(mx, off, 64));
    float l = 0.f;
#pragma unroll
    for (int c = 0; c < 8; ++c) { float e = __expf(pv[c] - mx); pv[c] = e; l += e; }
#pragma unroll
    for (int off = 8; off; off >>= 1) l += __shfl_xor(l, off, 64);
    float rinv = 1.f / l;
#pragma unroll
    for (int c = 0; c < 8; ++c)
      KsPs[(wave * 16 + quad * 4 + reg) * 136 + c * 16 + lr] = __float2bfloat16(pv[c] * rinv);
  }

  __hip_bfloat16* obase = o + (size_t)(b * TT) * DD + h * 64;
#pragma unroll
  for (int ct = 0; ct < 4; ++ct) {
    f32x4 acc = {};
#pragma unroll
    for (int kk = 0; kk < 4; ++kk) {
      bf16x8 pa = *(const bf16x8*)&KsPs[(wave * 16 + lr) * 136 + kk * 32 + quad * 8];
      int dd = ct * 16 + lr;
      bf16x8 vf = *(const bf16x8*)&Vt[dd * 136 + (((kk * 4 + quad) ^ (dd >> 3)) * 8)];
      acc = __builtin_amdgcn_mfma_f32_16x16x32_bf16(pa, vf, acc, 0, 0, 0);
    }
#pragma unroll
    for (int reg = 0; reg < 4; ++reg) {
      int t = t0 + wave * 16 + quad * 4 + reg;
      obase[(size_t)t * DD + ct * 16 + lr] = __float2bfloat16(acc[reg]);
    }
  }
}

extern "C" void kernel_launch(void* const* d_in, const int* in_sizes, int n_in,
                              void* d_out, int out_size, void* d_ws, size_t ws_size,
                              hipStream_t stream) {
  const float* tokens = (const float*)d_in[0];
  const float* Wqkv = (const float*)d_in[1];
  const float* bqkv = (const float*)d_in[2];
  const float* Wo   = (const float*)d_in[3];
  const float* bo   = (const float*)d_in[4];
  const float* W1   = (const float*)d_in[5];
  const float* b1   = (const float*)d_in[6];
  const float* W2   = (const float*)d_in[7];
  const float* b2   = (const float*)d_in[8];
  const float* ln1g = (const float*)d_in[9];
  const float* ln1b = (const float*)d_in[10];
  const float* ln2g = (const float*)d_in[11];
  const float* ln2b = (const float*)d_in[12];
  const float* lnfg = (const float*)d_in[13];
  const float* lnfb = (const float*)d_in[14];
  float* out = (float*)d_out;

  const int M = BB * TT;                 // 8192
  const int ND = M * DD;

  float* x = (float*)d_ws;
  __hip_bfloat16* sb  = (__hip_bfloat16*)(x + ND);
  __hip_bfloat16* big = sb + (size_t)M * DD;
  __hip_bfloat16* wqb = big + (size_t)M * FF;
  __hip_bfloat16* wob = wqb + (size_t)NL * 3 * DD * DD;
  __hip_bfloat16* w1b = wob + (size_t)NL * DD * DD;
  __hip_bfloat16* w2b = w1b + (size_t)NL * FF * DD;

  prologue_kernel<<<3072 + M / 4, 256, 0, stream>>>(
      (const float4*)Wqkv, (const float4*)Wo, (const float4*)W1,
      (const float4*)W2, (ushort4*)wqb, tokens, ln1g, ln1b, x, sb);

  // layer-0 qkv (later layers' qkv fused into mlp_kernel)
  mgemm_kernel<2, 4, 64, 256, 0><<<dim3(6, 128), 256, 0, stream>>>(
      sb, wqb, bqkv, big, M, 768);

  for (int l = 0; l < NL; ++l) {
    attn_kernel<<<dim3(TT / 64, BB * 4), 256, 0, stream>>>(big, sb);
    mgemm_ln_kernel<256, 0><<<M / 32, 256, 0, stream>>>(
        sb, wob + (size_t)l * DD * DD, bo + l * DD, x,
        ln2g + l * DD, ln2b + l * DD, x, sb);
    if (l < NL - 1) {
      mlp_kernel<0><<<M / 32, 256, 0, stream>>>(
          sb, w1b + (size_t)l * FF * DD, b1 + l * FF,
          w2b + (size_t)l * DD * FF, b2 + l * DD,
          wqb + (size_t)(l + 1) * 768 * DD, bqkv + (l + 1) * 768,
          ln1g + (l + 1) * DD, ln1b + (l + 1) * DD, x, big, nullptr);
    } else {
      mlp_kernel<1><<<M / 32, 256, 0, stream>>>(
          sb, w1b + (size_t)l * FF * DD, b1 + l * FF,
          w2b + (size_t)l * DD * FF, b2 + l * DD,
          nullptr, nullptr, lnfg, lnfb, x, nullptr, out);
    }
  }
}

// Round 11
// 366.651 us; speedup vs baseline: 1.0840x; 1.0840x over previous
//
#include <hip/hip_runtime.h>
#include <hip/hip_bf16.h>
#include <math.h>

#define BB 4
#define TT 2048
#define DD 256
#define FF 1024
#define NL 4

typedef __bf16 bf16x8 __attribute__((ext_vector_type(8)));
typedef float f32x4 __attribute__((ext_vector_type(4)));

__device__ __forceinline__ void stage16(const __hip_bfloat16* gp, __hip_bfloat16* lp) {
  __builtin_amdgcn_global_load_lds(
      (const __attribute__((address_space(1))) unsigned int*)gp,
      (__attribute__((address_space(3))) unsigned int*)lp, 16, 0, 0);
}

// fast exact-GELU: 0.5x(1+erf(x/sqrt2)), erf via A&S 7.1.26 (|err|<1.5e-7)
__device__ __forceinline__ float gelu_f(float v) {
  float x = fabsf(v) * 0.70710678118654752f;
  float t = 1.0f / fmaf(0.3275911f, x, 1.0f);
  float p = t * fmaf(t, fmaf(t, fmaf(t, fmaf(t, 1.061405429f, -1.453152027f),
                                     1.421413741f), -0.284496736f), 0.254829592f);
  float erfv = copysignf(1.0f - p * __expf(-x * x), v);
  return 0.5f * v * (1.0f + erfv);
}

// ---------------- prologue: weight f32->bf16 (blocks 0..3071) + PE+LN0 (rest) ----
__global__ __launch_bounds__(256) void prologue_kernel(
    const float4* __restrict__ wq, const float4* __restrict__ wo,
    const float4* __restrict__ w1, const float4* __restrict__ w2,
    ushort4* __restrict__ dst,
    const float* __restrict__ tokens, const float* __restrict__ g,
    const float* __restrict__ b, float* __restrict__ x,
    __hip_bfloat16* __restrict__ sb) {
  if (blockIdx.x < 3072) {
    int gi = blockIdx.x * 256 + threadIdx.x;
    const float4* src;
    int off;
    if (gi < 196608)      { src = wq; off = gi; }
    else if (gi < 262144) { src = wo; off = gi - 196608; }
    else if (gi < 524288) { src = w1; off = gi - 262144; }
    else                  { src = w2; off = gi - 524288; }
    float4 v = src[off];
    ushort4 o;
    o.x = __hip_bfloat16_raw(__float2bfloat16(v.x)).x;
    o.y = __hip_bfloat16_raw(__float2bfloat16(v.y)).x;
    o.z = __hip_bfloat16_raw(__float2bfloat16(v.z)).x;
    o.w = __hip_bfloat16_raw(__float2bfloat16(v.w)).x;
    dst[gi] = o;
    return;
  }
  int row = (blockIdx.x - 3072) * 4 + (threadIdx.x >> 6);
  int lane = threadIdx.x & 63;
  int t = row & (TT - 1);
  const float* xr = tokens + (size_t)row * DD;
  float v[4];
  float s = 0.f;
#pragma unroll
  for (int i = 0; i < 4; ++i) {
    int d = lane + 64 * i;
    int i2 = d & ~1;
    float freq = expf((float)i2 * -(9.210340371976184f / 256.f));
    float ang = (float)t * freq;
    float pe = (d & 1) ? cosf(ang) : sinf(ang);
    v[i] = xr[d] + pe;
    s += v[i];
  }
#pragma unroll
  for (int off = 32; off; off >>= 1) s += __shfl_xor(s, off, 64);
  float mu = s * (1.f / DD);
  float vs = 0.f;
#pragma unroll
  for (int i = 0; i < 4; ++i) { float dd = v[i] - mu; vs = fmaf(dd, dd, vs); }
#pragma unroll
  for (int off = 32; off; off >>= 1) vs += __shfl_xor(vs, off, 64);
  float rr = rsqrtf(vs * (1.f / DD) + 1e-5f);
#pragma unroll
  for (int i = 0; i < 4; ++i) {
    int d = lane + 64 * i;
    x[(size_t)row * DD + d] = v[i];
    sb[(size_t)row * DD + d] = __float2bfloat16((v[i] - mu) * rr * g[d] + b[d]);
  }
}

// ---------------- bf16 MFMA GEMM, chunked LDS (layer-0 qkv only) ----------
template <int MW, int NW, int BK, int KTOT, int ACT>
__global__ __launch_bounds__(256) void mgemm_kernel(
    const __hip_bfloat16* __restrict__ A, const __hip_bfloat16* __restrict__ B,
    const float* __restrict__ bias, __hip_bfloat16* __restrict__ Cout,
    int M, int N) {
  constexpr int BM = 32 * MW, BN = 32 * NW, ROWS = BM + BN;
  constexpr int NCH = BK / 32;
  constexpr int CHB = ROWS * 32;
  constexpr int RG = ROWS / 16;
  constexpr int NST = NCH * RG;
  __shared__ __align__(16) __hip_bfloat16 sm[NCH * CHB];
  const int tid = threadIdx.x;
  const int wave = tid >> 6, lane = tid & 63;
  const int m0 = blockIdx.y * BM, n0 = blockIdx.x * BN;
  const int wm = (wave >> 1) * (16 * MW), wn = (wave & 1) * (16 * NW);
  const int quad = lane >> 4, lr = lane & 15;
  const int srow = lane >> 2, scol = (lane & 3) * 8;

  f32x4 acc[MW][NW] = {};

  for (int kt = 0; kt < KTOT; kt += BK) {
    __syncthreads();
#pragma unroll
    for (int i = 0; i < NST / 4; ++i) {
      int inst = i * 4 + wave;
      int c = inst / RG, grp = inst - c * RG;
      int r = grp * 16 + srow;
      const __hip_bfloat16* gp =
          (r < BM) ? (A + (size_t)(m0 + r) * KTOT + kt + c * 32 + scol)
                   : (B + (size_t)(n0 + (r - BM)) * KTOT + kt + c * 32 + scol);
      stage16(gp, sm + c * CHB + grp * 512);
    }
    __syncthreads();
#pragma unroll
    for (int c = 0; c < NCH; ++c) {
      bf16x8 af[MW], bfr[NW];
#pragma unroll
      for (int mi = 0; mi < MW; ++mi)
        af[mi] = *(const bf16x8*)(sm + c * CHB + (wm + mi * 16 + lr) * 32 + quad * 8);
#pragma unroll
      for (int ni = 0; ni < NW; ++ni)
        bfr[ni] = *(const bf16x8*)(sm + c * CHB + (BM + wn + ni * 16 + lr) * 32 + quad * 8);
#pragma unroll
      for (int mi = 0; mi < MW; ++mi)
#pragma unroll
        for (int ni = 0; ni < NW; ++ni)
          acc[mi][ni] = __builtin_amdgcn_mfma_f32_16x16x32_bf16(
              af[mi], bfr[ni], acc[mi][ni], 0, 0, 0);
    }
  }

#pragma unroll
  for (int mi = 0; mi < MW; ++mi) {
#pragma unroll
    for (int ni = 0; ni < NW; ++ni) {
      int col = n0 + wn + ni * 16 + lr;
      float bv = bias[col];
#pragma unroll
      for (int r = 0; r < 4; ++r) {
        int row = m0 + wm + mi * 16 + quad * 4 + r;
        float v = acc[mi][ni][r] + bv;
        if (ACT == 1) v = gelu_f(v);
        Cout[(size_t)row * N + col] = __float2bfloat16(v);
      }
    }
  }
}

// ---------------- bf16 GEMM, N=256 full-row, fused residual+LN (Wo path) ----
template <int KTOT, int FIN>
__global__ __launch_bounds__(256) void mgemm_ln_kernel(
    const __hip_bfloat16* __restrict__ A, const __hip_bfloat16* __restrict__ B,
    const float* __restrict__ bias, const float* __restrict__ res,
    const float* __restrict__ g, const float* __restrict__ bb,
    float* __restrict__ xout, void* __restrict__ yout) {
  constexpr int BM = 32, ROWS = BM + 256;
  constexpr int BK = 64, NCH = BK / 32;
  constexpr int CHB = ROWS * 32;
  constexpr int RG = ROWS / 16;
  constexpr int NST = NCH * RG;
  __shared__ __align__(16) __hip_bfloat16 sm[NCH * CHB];
  __shared__ float red1[4][BM], red2[4][BM];
  const int tid = threadIdx.x;
  const int wave = tid >> 6, lane = tid & 63;
  const int quad = lane >> 4, lr = lane & 15;
  const int m0 = blockIdx.x * BM;
  const int srow = lane >> 2, scol = (lane & 3) * 8;

  f32x4 acc[2][4] = {};

  for (int kt = 0; kt < KTOT; kt += BK) {
    __syncthreads();
#pragma unroll
    for (int i = 0; i < NST / 4; ++i) {
      int inst = i * 4 + wave;
      int c = inst / RG, grp = inst - c * RG;
      int r = grp * 16 + srow;
      const __hip_bfloat16* gp =
          (r < BM) ? (A + (size_t)(m0 + r) * KTOT + kt + c * 32 + scol)
                   : (B + (size_t)(r - BM) * KTOT + kt + c * 32 + scol);
      stage16(gp, sm + c * CHB + grp * 512);
    }
    __syncthreads();
#pragma unroll
    for (int c = 0; c < NCH; ++c) {
      bf16x8 af[2], bfr[4];
#pragma unroll
      for (int mi = 0; mi < 2; ++mi)
        af[mi] = *(const bf16x8*)(sm + c * CHB + (mi * 16 + lr) * 32 + quad * 8);
#pragma unroll
      for (int ni = 0; ni < 4; ++ni)
        bfr[ni] = *(const bf16x8*)(sm + c * CHB + (BM + wave * 64 + ni * 16 + lr) * 32 + quad * 8);
#pragma unroll
      for (int mi = 0; mi < 2; ++mi)
#pragma unroll
        for (int ni = 0; ni < 4; ++ni)
          acc[mi][ni] = __builtin_amdgcn_mfma_f32_16x16x32_bf16(
              af[mi], bfr[ni], acc[mi][ni], 0, 0, 0);
    }
  }

  float v[2][4][4];
  float s1[2][4] = {}, s2[2][4] = {};
#pragma unroll
  for (int mi = 0; mi < 2; ++mi)
#pragma unroll
    for (int ni = 0; ni < 4; ++ni) {
      int col = wave * 64 + ni * 16 + lr;
      float bv = bias[col];
#pragma unroll
      for (int r = 0; r < 4; ++r) {
        int row = m0 + mi * 16 + quad * 4 + r;
        float val = acc[mi][ni][r] + bv + res[(size_t)row * DD + col];
        v[mi][ni][r] = val;
        s1[mi][r] += val;
        s2[mi][r] = fmaf(val, val, s2[mi][r]);
      }
    }
#pragma unroll
  for (int mi = 0; mi < 2; ++mi)
#pragma unroll
    for (int r = 0; r < 4; ++r) {
#pragma unroll
      for (int off = 8; off; off >>= 1) {
        s1[mi][r] += __shfl_xor(s1[mi][r], off, 64);
        s2[mi][r] += __shfl_xor(s2[mi][r], off, 64);
      }
    }
  if (lr == 0) {
#pragma unroll
    for (int mi = 0; mi < 2; ++mi)
#pragma unroll
      for (int r = 0; r < 4; ++r) {
        red1[wave][mi * 16 + quad * 4 + r] = s1[mi][r];
        red2[wave][mi * 16 + quad * 4 + r] = s2[mi][r];
      }
  }
  __syncthreads();
#pragma unroll
  for (int mi = 0; mi < 2; ++mi)
#pragma unroll
    for (int r = 0; r < 4; ++r) {
      int rl = mi * 16 + quad * 4 + r;
      float ssum = red1[0][rl] + red1[1][rl] + red1[2][rl] + red1[3][rl];
      float qsum = red2[0][rl] + red2[1][rl] + red2[2][rl] + red2[3][rl];
      float mu = ssum * (1.f / DD);
      float var = qsum * (1.f / DD) - mu * mu;
      float rr = rsqrtf(var + 1e-5f);
      int row = m0 + rl;
#pragma unroll
      for (int ni = 0; ni < 4; ++ni) {
        int col = wave * 64 + ni * 16 + lr;
        float y = (v[mi][ni][r] - mu) * rr * g[col] + bb[col];
        if (FIN) {
          ((float*)yout)[(size_t)row * DD + col] = y;
        } else {
          ((__hip_bfloat16*)yout)[(size_t)row * DD + col] = __float2bfloat16(y);
          xout[(size_t)row * DD + col] = v[mi][ni][r];
        }
      }
    }
}

// ---------------- fused MLP (+ next-layer qkv), BM=16, grid 512, 2 blocks/CU ----
// Block owns 16 rows. h = gelu(A@W1^T+b1) per 128-ff chunk -> hbuf ->
// xacc += h@W2c^T. Epilogue: v = xacc+b2+x -> LN -> (LAST: fp32 out) or
// (x write + sbuf2 -> qkv(l+1) -> big). LDS ~54 KB.
template <int LAST>
__global__ __launch_bounds__(256) void mlp_kernel(
    const __hip_bfloat16* __restrict__ sb, const __hip_bfloat16* __restrict__ w1,
    const float* __restrict__ b1, const __hip_bfloat16* __restrict__ w2,
    const float* __restrict__ b2, const __hip_bfloat16* __restrict__ wq,
    const float* __restrict__ bq, const float* __restrict__ g,
    const float* __restrict__ bb, float* __restrict__ x,
    __hip_bfloat16* __restrict__ big, float* __restrict__ out) {
  __shared__ __align__(16) __hip_bfloat16 asbuf[4096];   // A (ln2-out) 16x256 chunked
  __shared__ __align__(16) __hip_bfloat16 sbuf2[4096];   // ln1(l+1) 16x256 chunked
  __shared__ __align__(16) __hip_bfloat16 hbuf[16 * 136];// gelu-h 16x128
  __shared__ __align__(16) __hip_bfloat16 wstage[16384]; // 32 KB weight stage
  __shared__ float red1[4][16], red2[4][16];
  const int tid = threadIdx.x;
  const int wave = tid >> 6, lane = tid & 63;
  const int quad = lane >> 4, lr = lane & 15;
  const int srow = lane >> 2, scol = (lane & 3) * 8;
  const int t0 = blockIdx.x * 16;

  // stage A (sb rows t0..t0+15) into chunked layout [c][16r][32k]
  {
    int inst = 0 * 4 + wave;  // two rounds: insts 0..7 = chunks 0..7
#pragma unroll
    for (int i = 0; i < 2; ++i) {
      int c = i * 4 + wave;
      stage16(sb + (size_t)(t0 + srow) * 256 + c * 32 + scol, asbuf + c * 512);
    }
    (void)inst;
  }
  __syncthreads();

  f32x4 xacc[4] = {};
  for (int fc = 0; fc < 8; ++fc) {
    const int ff0 = fc * 128;
    f32x4 hacc[2] = {};
#pragma unroll
    for (int kt2 = 0; kt2 < 2; ++kt2) {
      __syncthreads();                     // protect wstage (+hbuf cycle)
#pragma unroll
      for (int i = 0; i < 8; ++i) {
        int inst = i * 4 + wave;           // 0..31
        int c2 = inst >> 3, grp = inst & 7;
        int r = grp * 16 + srow;
        stage16(w1 + (size_t)(ff0 + r) * 256 + kt2 * 128 + c2 * 32 + scol,
                wstage + c2 * 4096 + grp * 512);
      }
      __syncthreads();
#pragma unroll
      for (int c2 = 0; c2 < 4; ++c2) {
        bf16x8 af = *(const bf16x8*)(asbuf + (kt2 * 4 + c2) * 512 + lr * 32 + quad * 8);
        bf16x8 bfr[2];
#pragma unroll
        for (int ni = 0; ni < 2; ++ni)
          bfr[ni] = *(const bf16x8*)(wstage + c2 * 4096 + (wave * 32 + ni * 16 + lr) * 32 + quad * 8);
#pragma unroll
        for (int ni = 0; ni < 2; ++ni)
          hacc[ni] = __builtin_amdgcn_mfma_f32_16x16x32_bf16(af, bfr[ni], hacc[ni], 0, 0, 0);
      }
    }
    // gelu -> hbuf (wave writes its own 32-col strip)
#pragma unroll
    for (int ni = 0; ni < 2; ++ni) {
      int col = wave * 32 + ni * 16 + lr;
      float bv = b1[ff0 + col];
#pragma unroll
      for (int r = 0; r < 4; ++r)
        hbuf[(quad * 4 + r) * 136 + col] = __float2bfloat16(gelu_f(hacc[ni][r] + bv));
    }
    __syncthreads();                       // hbuf ready, W1 wstage reads done
#pragma unroll
    for (int kt3 = 0; kt3 < 2; ++kt3) {
      if (kt3) __syncthreads();            // wstage reuse between kt3 iters
#pragma unroll
      for (int i = 0; i < 8; ++i) {
        int inst = i * 4 + wave;           // 0..31
        int c2 = inst >> 4, grp = inst & 15;
        int r = grp * 16 + srow;
        stage16(w2 + (size_t)r * 1024 + ff0 + kt3 * 64 + c2 * 32 + scol,
                wstage + c2 * 8192 + grp * 512);
      }
      __syncthreads();
#pragma unroll
      for (int c2 = 0; c2 < 2; ++c2) {
        bf16x8 af = *(const bf16x8*)(hbuf + lr * 136 + kt3 * 64 + c2 * 32 + quad * 8);
        bf16x8 bfr[4];
#pragma unroll
        for (int ni = 0; ni < 4; ++ni)
          bfr[ni] = *(const bf16x8*)(wstage + c2 * 8192 + (wave * 64 + ni * 16 + lr) * 32 + quad * 8);
#pragma unroll
        for (int ni = 0; ni < 4; ++ni)
          xacc[ni] = __builtin_amdgcn_mfma_f32_16x16x32_bf16(af, bfr[ni], xacc[ni], 0, 0, 0);
      }
    }
  }

  // epilogue: v = xacc + b2 + x; LN over the 16 rows
  float v[4][4];
  float s1[4] = {}, s2[4] = {};
#pragma unroll
  for (int ni = 0; ni < 4; ++ni) {
    int col = wave * 64 + ni * 16 + lr;
    float bv = b2[col];
#pragma unroll
    for (int r = 0; r < 4; ++r) {
      int row = t0 + quad * 4 + r;
      float val = xacc[ni][r] + bv + x[(size_t)row * DD + col];
      v[ni][r] = val;
      s1[r] += val;
      s2[r] = fmaf(val, val, s2[r]);
    }
  }
#pragma unroll
  for (int r = 0; r < 4; ++r) {
#pragma unroll
    for (int off = 8; off; off >>= 1) {
      s1[r] += __shfl_xor(s1[r], off, 64);
      s2[r] += __shfl_xor(s2[r], off, 64);
    }
  }
  if (lr == 0) {
#pragma unroll
    for (int r = 0; r < 4; ++r) {
      red1[wave][quad * 4 + r] = s1[r];
      red2[wave][quad * 4 + r] = s2[r];
    }
  }
  __syncthreads();
#pragma unroll
  for (int r = 0; r < 4; ++r) {
    int rl = quad * 4 + r;
    float ssum = red1[0][rl] + red1[1][rl] + red1[2][rl] + red1[3][rl];
    float qsum = red2[0][rl] + red2[1][rl] + red2[2][rl] + red2[3][rl];
    float mu = ssum * (1.f / DD);
    float var = qsum * (1.f / DD) - mu * mu;
    float rr = rsqrtf(var + 1e-5f);
    int row = t0 + rl;
#pragma unroll
    for (int ni = 0; ni < 4; ++ni) {
      int col = wave * 64 + ni * 16 + lr;
      float y = (v[ni][r] - mu) * rr * g[col] + bb[col];
      if (LAST) {
        out[(size_t)row * DD + col] = y;
      } else {
        x[(size_t)row * DD + col] = v[ni][r];
        sbuf2[(col >> 5) * 512 + rl * 32 + (col & 31)] = __float2bfloat16(y);
      }
    }
  }

  if (!LAST) {
    __syncthreads();                       // sbuf2 ready
    for (int nc = 0; nc < 6; ++nc) {
      f32x4 qacc[2] = {};
#pragma unroll
      for (int kt2 = 0; kt2 < 2; ++kt2) {
        __syncthreads();                   // wstage reuse
#pragma unroll
        for (int i = 0; i < 8; ++i) {
          int inst = i * 4 + wave;
          int c2 = inst >> 3, grp = inst & 7;
          int r = grp * 16 + srow;
          stage16(wq + (size_t)(nc * 128 + r) * 256 + kt2 * 128 + c2 * 32 + scol,
                  wstage + c2 * 4096 + grp * 512);
        }
        __syncthreads();
#pragma unroll
        for (int c2 = 0; c2 < 4; ++c2) {
          bf16x8 af = *(const bf16x8*)(sbuf2 + (kt2 * 4 + c2) * 512 + lr * 32 + quad * 8);
          bf16x8 bfr[2];
#pragma unroll
          for (int ni = 0; ni < 2; ++ni)
            bfr[ni] = *(const bf16x8*)(wstage + c2 * 4096 + (wave * 32 + ni * 16 + lr) * 32 + quad * 8);
#pragma unroll
          for (int ni = 0; ni < 2; ++ni)
            qacc[ni] = __builtin_amdgcn_mfma_f32_16x16x32_bf16(af, bfr[ni], qacc[ni], 0, 0, 0);
        }
      }
#pragma unroll
      for (int ni = 0; ni < 2; ++ni) {
        int col = nc * 128 + wave * 32 + ni * 16 + lr;
        float bv = bq[col];
#pragma unroll
        for (int r = 0; r < 4; ++r) {
          int row = t0 + quad * 4 + r;
          big[(size_t)row * 768 + col] = __float2bfloat16(qacc[ni][r] + bv);
        }
      }
    }
  }
}

// ---------------- sliding-window attention, MFMA (R9, unchanged) ----------------
__global__ __launch_bounds__(256) void attn_kernel(const __hip_bfloat16* __restrict__ qkv,
                                                   __hip_bfloat16* __restrict__ o) {
  __shared__ __align__(16) __hip_bfloat16 KsPs[128 * 72];
  __shared__ __align__(16) __hip_bfloat16 Vt[64 * 136];
  const int bh = blockIdx.y;
  const int b = bh >> 2, h = bh & 3;
  const int t0 = blockIdx.x * 64;
  const int sbase = t0 - 63;
  const int tid = threadIdx.x;

  const __hip_bfloat16* kb = qkv + (size_t)(b * TT) * 768 + 256 + h * 64;
  const __hip_bfloat16* vb = kb + 256;
  union U8 { uint4 u; __hip_bfloat16 hx[8]; };
#pragma unroll
  for (int it = 0; it < 4; ++it) {
    int f = tid + it * 256;
    int si = f >> 3;
    int c8 = f & 7;
    int s = sbase + si;
    U8 kr, vr;
    kr.u = make_uint4(0, 0, 0, 0); vr.u = make_uint4(0, 0, 0, 0);
    if (s >= 0 && s < TT) {
      kr.u = *(const uint4*)&kb[(size_t)s * 768 + 8 * c8];
      vr.u = *(const uint4*)&vb[(size_t)s * 768 + 8 * c8];
    }
    *(uint4*)&KsPs[si * 72 + c8 * 8] = kr.u;
    int pc = (si >> 3) ^ c8;
#pragma unroll
    for (int j = 0; j < 8; ++j) Vt[(c8 * 8 + j) * 136 + pc * 8 + (si & 7)] = vr.hx[j];
  }
  __syncthreads();

  const int wave = tid >> 6, lane = tid & 63;
  const int quad = lane >> 4, lr = lane & 15;

  const __hip_bfloat16* qrow = qkv + (size_t)(b * TT + t0 + wave * 16 + lr) * 768 + h * 64;
  bf16x8 qa0 = *(const bf16x8*)(qrow + quad * 8);
  bf16x8 qa1 = *(const bf16x8*)(qrow + 32 + quad * 8);
  f32x4 sc[8];
#pragma unroll
  for (int c = 0; c < 8; ++c) {
    f32x4 a = {};
    bf16x8 kf0 = *(const bf16x8*)&KsPs[(c * 16 + lr) * 72 + quad * 8];
    a = __builtin_amdgcn_mfma_f32_16x16x32_bf16(qa0, kf0, a, 0, 0, 0);
    bf16x8 kf1 = *(const bf16x8*)&KsPs[(c * 16 + lr) * 72 + 32 + quad * 8];
    a = __builtin_amdgcn_mfma_f32_16x16x32_bf16(qa1, kf1, a, 0, 0, 0);
    sc[c] = a;
  }
  __syncthreads();

#pragma unroll
  for (int reg = 0; reg < 4; ++reg) {
    int dt = wave * 16 + quad * 4 + reg;
    float pv[8];
    float mx = -1e30f;
#pragma unroll
    for (int c = 0; c < 8; ++c) {
      int si = c * 16 + lr;
      float v = sc[c][reg] * 0.125f;
      bool ok = (si >= dt) && (si <= dt + 63) && (sbase + si >= 0);
      v = ok ? v : -1e30f;
      pv[c] = v;
      mx = fmaxf(mx, v);
    }
#pragma unroll
    for (int off = 8; off; off >>= 1) mx = fmaxf(mx, __shfl_xor(mx, off, 64));
    float l = 0.f;
#pragma unroll
    for (int c = 0; c < 8; ++c) { float e = __expf(pv[c] - mx); pv[c] = e; l += e; }
#pragma unroll
    for (int off = 8; off; off >>= 1) l += __shfl_xor(l, off, 64);
    float rinv = 1.f / l;
#pragma unroll
    for (int c = 0; c < 8; ++c)
      KsPs[(wave * 16 + quad * 4 + reg) * 136 + c * 16 + lr] = __float2bfloat16(pv[c] * rinv);
  }

  __hip_bfloat16* obase = o + (size_t)(b * TT) * DD + h * 64;
#pragma unroll
  for (int ct = 0; ct < 4; ++ct) {
    f32x4 acc = {};
#pragma unroll
    for (int kk = 0; kk < 4; ++kk) {
      bf16x8 pa = *(const bf16x8*)&KsPs[(wave * 16 + lr) * 136 + kk * 32 + quad * 8];
      int dd = ct * 16 + lr;
      bf16x8 vf = *(const bf16x8*)&Vt[dd * 136 + (((kk * 4 + quad) ^ (dd >> 3)) * 8)];
      acc = __builtin_amdgcn_mfma_f32_16x16x32_bf16(pa, vf, acc, 0, 0, 0);
    }
#pragma unroll
    for (int reg = 0; reg < 4; ++reg) {
      int t = t0 + wave * 16 + quad * 4 + reg;
      obase[(size_t)t * DD + ct * 16 + lr] = __float2bfloat16(acc[reg]);
    }
  }
}

extern "C" void kernel_launch(void* const* d_in, const int* in_sizes, int n_in,
                              void* d_out, int out_size, void* d_ws, size_t ws_size,
                              hipStream_t stream) {
  const float* tokens = (const float*)d_in[0];
  const float* Wqkv = (const float*)d_in[1];
  const float* bqkv = (const float*)d_in[2];
  const float* Wo   = (const float*)d_in[3];
  const float* bo   = (const float*)d_in[4];
  const float* W1   = (const float*)d_in[5];
  const float* b1   = (const float*)d_in[6];
  const float* W2   = (const float*)d_in[7];
  const float* b2   = (const float*)d_in[8];
  const float* ln1g = (const float*)d_in[9];
  const float* ln1b = (const float*)d_in[10];
  const float* ln2g = (const float*)d_in[11];
  const float* ln2b = (const float*)d_in[12];
  const float* lnfg = (const float*)d_in[13];
  const float* lnfb = (const float*)d_in[14];
  float* out = (float*)d_out;

  const int M = BB * TT;                 // 8192
  const int ND = M * DD;

  float* x = (float*)d_ws;
  __hip_bfloat16* sb  = (__hip_bfloat16*)(x + ND);
  __hip_bfloat16* big = sb + (size_t)M * DD;
  __hip_bfloat16* wqb = big + (size_t)M * FF;
  __hip_bfloat16* wob = wqb + (size_t)NL * 3 * DD * DD;
  __hip_bfloat16* w1b = wob + (size_t)NL * DD * DD;
  __hip_bfloat16* w2b = w1b + (size_t)NL * FF * DD;

  prologue_kernel<<<3072 + M / 4, 256, 0, stream>>>(
      (const float4*)Wqkv, (const float4*)Wo, (const float4*)W1,
      (const float4*)W2, (ushort4*)wqb, tokens, ln1g, ln1b, x, sb);

  // layer-0 qkv (later layers' qkv fused into mlp_kernel)
  mgemm_kernel<2, 4, 64, 256, 0><<<dim3(6, 128), 256, 0, stream>>>(
      sb, wqb, bqkv, big, M, 768);

  for (int l = 0; l < NL; ++l) {
    attn_kernel<<<dim3(TT / 64, BB * 4), 256, 0, stream>>>(big, sb);
    mgemm_ln_kernel<256, 0><<<M / 32, 256, 0, stream>>>(
        sb, wob + (size_t)l * DD * DD, bo + l * DD, x,
        ln2g + l * DD, ln2b + l * DD, x, sb);
    if (l < NL - 1) {
      mlp_kernel<0><<<M / 16, 256, 0, stream>>>(
          sb, w1b + (size_t)l * FF * DD, b1 + l * FF,
          w2b + (size_t)l * DD * FF, b2 + l * DD,
          wqb + (size_t)(l + 1) * 768 * DD, bqkv + (l + 1) * 768,
          ln1g + (l + 1) * DD, ln1b + (l + 1) * DD, x, big, nullptr);
    } else {
      mlp_kernel<1><<<M / 16, 256, 0, stream>>>(
          sb, w1b + (size_t)l * FF * DD, b1 + l * FF,
          w2b + (size_t)l * DD * FF, b2 + l * DD,
          nullptr, nullptr, lnfg, lnfb, x, nullptr, out);
    }
  }
}

// Round 12
// 361.142 us; speedup vs baseline: 1.1006x; 1.0153x over previous
//
#include <hip/hip_runtime.h>
#include <hip/hip_bf16.h>
#include <math.h>

#define BB 4
#define TT 2048
#define DD 256
#define FF 1024
#define NL 4

typedef __bf16 bf16x8 __attribute__((ext_vector_type(8)));
typedef float f32x4 __attribute__((ext_vector_type(4)));

__device__ __forceinline__ void stage16(const __hip_bfloat16* gp, __hip_bfloat16* lp) {
  __builtin_amdgcn_global_load_lds(
      (const __attribute__((address_space(1))) unsigned int*)gp,
      (__attribute__((address_space(3))) unsigned int*)lp, 16, 0, 0);
}

// fast exact-GELU: 0.5x(1+erf(x/sqrt2)), erf via A&S 7.1.26 (|err|<1.5e-7)
__device__ __forceinline__ float gelu_f(float v) {
  float x = fabsf(v) * 0.70710678118654752f;
  float t = 1.0f / fmaf(0.3275911f, x, 1.0f);
  float p = t * fmaf(t, fmaf(t, fmaf(t, fmaf(t, 1.061405429f, -1.453152027f),
                                     1.421413741f), -0.284496736f), 0.254829592f);
  float erfv = copysignf(1.0f - p * __expf(-x * x), v);
  return 0.5f * v * (1.0f + erfv);
}

// ---------------- prologue: weight f32->bf16 (blocks 0..3071) + PE+LN0 (rest) ----
__global__ __launch_bounds__(256) void prologue_kernel(
    const float4* __restrict__ wq, const float4* __restrict__ wo,
    const float4* __restrict__ w1, const float4* __restrict__ w2,
    ushort4* __restrict__ dst,
    const float* __restrict__ tokens, const float* __restrict__ g,
    const float* __restrict__ b, float* __restrict__ x,
    __hip_bfloat16* __restrict__ sb) {
  if (blockIdx.x < 3072) {
    int gi = blockIdx.x * 256 + threadIdx.x;
    const float4* src;
    int off;
    if (gi < 196608)      { src = wq; off = gi; }
    else if (gi < 262144) { src = wo; off = gi - 196608; }
    else if (gi < 524288) { src = w1; off = gi - 262144; }
    else                  { src = w2; off = gi - 524288; }
    float4 v = src[off];
    ushort4 o;
    o.x = __hip_bfloat16_raw(__float2bfloat16(v.x)).x;
    o.y = __hip_bfloat16_raw(__float2bfloat16(v.y)).x;
    o.z = __hip_bfloat16_raw(__float2bfloat16(v.z)).x;
    o.w = __hip_bfloat16_raw(__float2bfloat16(v.w)).x;
    dst[gi] = o;
    return;
  }
  int row = (blockIdx.x - 3072) * 4 + (threadIdx.x >> 6);
  int lane = threadIdx.x & 63;
  int t = row & (TT - 1);
  const float* xr = tokens + (size_t)row * DD;
  float v[4];
  float s = 0.f;
#pragma unroll
  for (int i = 0; i < 4; ++i) {
    int d = lane + 64 * i;
    int i2 = d & ~1;
    float freq = expf((float)i2 * -(9.210340371976184f / 256.f));
    float ang = (float)t * freq;
    float pe = (d & 1) ? cosf(ang) : sinf(ang);
    v[i] = xr[d] + pe;
    s += v[i];
  }
#pragma unroll
  for (int off = 32; off; off >>= 1) s += __shfl_xor(s, off, 64);
  float mu = s * (1.f / DD);
  float vs = 0.f;
#pragma unroll
  for (int i = 0; i < 4; ++i) { float dd = v[i] - mu; vs = fmaf(dd, dd, vs); }
#pragma unroll
  for (int off = 32; off; off >>= 1) vs += __shfl_xor(vs, off, 64);
  float rr = rsqrtf(vs * (1.f / DD) + 1e-5f);
#pragma unroll
  for (int i = 0; i < 4; ++i) {
    int d = lane + 64 * i;
    x[(size_t)row * DD + d] = v[i];
    sb[(size_t)row * DD + d] = __float2bfloat16((v[i] - mu) * rr * g[d] + b[d]);
  }
}

// ---------------- bf16 MFMA GEMM, chunked LDS ----------
// Block tile 32MW x 32NW, 4 waves 2x2. OUTF: 0=bf16 out, 1=fp32 out.
template <int MW, int NW, int BK, int KTOT, int ACT, int OUTF>
__global__ __launch_bounds__(256) void mgemm_kernel(
    const __hip_bfloat16* __restrict__ A, const __hip_bfloat16* __restrict__ B,
    const float* __restrict__ bias, void* __restrict__ Cout,
    int M, int N) {
  constexpr int BM = 32 * MW, BN = 32 * NW, ROWS = BM + BN;
  constexpr int NCH = BK / 32;
  constexpr int CHB = ROWS * 32;
  constexpr int RG = ROWS / 16;
  constexpr int NST = NCH * RG;
  __shared__ __align__(16) __hip_bfloat16 sm[NCH * CHB];
  const int tid = threadIdx.x;
  const int wave = tid >> 6, lane = tid & 63;
  const int m0 = blockIdx.y * BM, n0 = blockIdx.x * BN;
  const int wm = (wave >> 1) * (16 * MW), wn = (wave & 1) * (16 * NW);
  const int quad = lane >> 4, lr = lane & 15;
  const int srow = lane >> 2, scol = (lane & 3) * 8;

  f32x4 acc[MW][NW] = {};

  for (int kt = 0; kt < KTOT; kt += BK) {
    __syncthreads();
#pragma unroll
    for (int i = 0; i < NST / 4; ++i) {
      int inst = i * 4 + wave;
      int c = inst / RG, grp = inst - c * RG;
      int r = grp * 16 + srow;
      const __hip_bfloat16* gp =
          (r < BM) ? (A + (size_t)(m0 + r) * KTOT + kt + c * 32 + scol)
                   : (B + (size_t)(n0 + (r - BM)) * KTOT + kt + c * 32 + scol);
      stage16(gp, sm + c * CHB + grp * 512);
    }
    __syncthreads();
#pragma unroll
    for (int c = 0; c < NCH; ++c) {
      bf16x8 af[MW], bfr[NW];
#pragma unroll
      for (int mi = 0; mi < MW; ++mi)
        af[mi] = *(const bf16x8*)(sm + c * CHB + (wm + mi * 16 + lr) * 32 + quad * 8);
#pragma unroll
      for (int ni = 0; ni < NW; ++ni)
        bfr[ni] = *(const bf16x8*)(sm + c * CHB + (BM + wn + ni * 16 + lr) * 32 + quad * 8);
#pragma unroll
      for (int mi = 0; mi < MW; ++mi)
#pragma unroll
        for (int ni = 0; ni < NW; ++ni)
          acc[mi][ni] = __builtin_amdgcn_mfma_f32_16x16x32_bf16(
              af[mi], bfr[ni], acc[mi][ni], 0, 0, 0);
    }
  }

#pragma unroll
  for (int mi = 0; mi < MW; ++mi) {
#pragma unroll
    for (int ni = 0; ni < NW; ++ni) {
      int col = n0 + wn + ni * 16 + lr;
      float bv = bias[col];
#pragma unroll
      for (int r = 0; r < 4; ++r) {
        int row = m0 + wm + mi * 16 + quad * 4 + r;
        float v = acc[mi][ni][r] + bv;
        if (ACT == 1) v = gelu_f(v);
        if (OUTF) ((float*)Cout)[(size_t)row * N + col] = v;
        else ((__hip_bfloat16*)Cout)[(size_t)row * N + col] = __float2bfloat16(v);
      }
    }
  }
}

// ---------------- bf16 GEMM, N=256 full-row, fused residual+LN (Wo path only) ----
template <int KTOT>
__global__ __launch_bounds__(256) void mgemm_ln_kernel(
    const __hip_bfloat16* __restrict__ A, const __hip_bfloat16* __restrict__ B,
    const float* __restrict__ bias, const float* __restrict__ res,
    const float* __restrict__ g, const float* __restrict__ bb,
    float* __restrict__ xout, __hip_bfloat16* __restrict__ yout) {
  constexpr int BM = 32, ROWS = BM + 256;
  constexpr int BK = 64, NCH = BK / 32;
  constexpr int CHB = ROWS * 32;
  constexpr int RG = ROWS / 16;
  constexpr int NST = NCH * RG;
  __shared__ __align__(16) __hip_bfloat16 sm[NCH * CHB];
  __shared__ float red1[4][BM], red2[4][BM];
  const int tid = threadIdx.x;
  const int wave = tid >> 6, lane = tid & 63;
  const int quad = lane >> 4, lr = lane & 15;
  const int m0 = blockIdx.x * BM;
  const int srow = lane >> 2, scol = (lane & 3) * 8;

  f32x4 acc[2][4] = {};

  for (int kt = 0; kt < KTOT; kt += BK) {
    __syncthreads();
#pragma unroll
    for (int i = 0; i < NST / 4; ++i) {
      int inst = i * 4 + wave;
      int c = inst / RG, grp = inst - c * RG;
      int r = grp * 16 + srow;
      const __hip_bfloat16* gp =
          (r < BM) ? (A + (size_t)(m0 + r) * KTOT + kt + c * 32 + scol)
                   : (B + (size_t)(r - BM) * KTOT + kt + c * 32 + scol);
      stage16(gp, sm + c * CHB + grp * 512);
    }
    __syncthreads();
#pragma unroll
    for (int c = 0; c < NCH; ++c) {
      bf16x8 af[2], bfr[4];
#pragma unroll
      for (int mi = 0; mi < 2; ++mi)
        af[mi] = *(const bf16x8*)(sm + c * CHB + (mi * 16 + lr) * 32 + quad * 8);
#pragma unroll
      for (int ni = 0; ni < 4; ++ni)
        bfr[ni] = *(const bf16x8*)(sm + c * CHB + (BM + wave * 64 + ni * 16 + lr) * 32 + quad * 8);
#pragma unroll
      for (int mi = 0; mi < 2; ++mi)
#pragma unroll
        for (int ni = 0; ni < 4; ++ni)
          acc[mi][ni] = __builtin_amdgcn_mfma_f32_16x16x32_bf16(
              af[mi], bfr[ni], acc[mi][ni], 0, 0, 0);
    }
  }

  float v[2][4][4];
  float s1[2][4] = {}, s2[2][4] = {};
#pragma unroll
  for (int mi = 0; mi < 2; ++mi)
#pragma unroll
    for (int ni = 0; ni < 4; ++ni) {
      int col = wave * 64 + ni * 16 + lr;
      float bv = bias[col];
#pragma unroll
      for (int r = 0; r < 4; ++r) {
        int row = m0 + mi * 16 + quad * 4 + r;
        float val = acc[mi][ni][r] + bv + res[(size_t)row * DD + col];
        v[mi][ni][r] = val;
        s1[mi][r] += val;
        s2[mi][r] = fmaf(val, val, s2[mi][r]);
      }
    }
#pragma unroll
  for (int mi = 0; mi < 2; ++mi)
#pragma unroll
    for (int r = 0; r < 4; ++r) {
#pragma unroll
      for (int off = 8; off; off >>= 1) {
        s1[mi][r] += __shfl_xor(s1[mi][r], off, 64);
        s2[mi][r] += __shfl_xor(s2[mi][r], off, 64);
      }
    }
  if (lr == 0) {
#pragma unroll
    for (int mi = 0; mi < 2; ++mi)
#pragma unroll
      for (int r = 0; r < 4; ++r) {
        red1[wave][mi * 16 + quad * 4 + r] = s1[mi][r];
        red2[wave][mi * 16 + quad * 4 + r] = s2[mi][r];
      }
  }
  __syncthreads();
#pragma unroll
  for (int mi = 0; mi < 2; ++mi)
#pragma unroll
    for (int r = 0; r < 4; ++r) {
      int rl = mi * 16 + quad * 4 + r;
      float ssum = red1[0][rl] + red1[1][rl] + red1[2][rl] + red1[3][rl];
      float qsum = red2[0][rl] + red2[1][rl] + red2[2][rl] + red2[3][rl];
      float mu = ssum * (1.f / DD);
      float var = qsum * (1.f / DD) - mu * mu;
      float rr = rsqrtf(var + 1e-5f);
      int row = m0 + rl;
#pragma unroll
      for (int ni = 0; ni < 4; ++ni) {
        int col = wave * 64 + ni * 16 + lr;
        float y = (v[mi][ni][r] - mu) * rr * g[col] + bb[col];
        yout[(size_t)row * DD + col] = __float2bfloat16(y);
        xout[(size_t)row * DD + col] = v[mi][ni][r];
      }
    }
}

// ---------------- residual + LayerNorm (elementwise, 1 wave/row) ----------------
// val = go[row][d] + xin[row][d]; FIN=0: x=val, sb=bf16(LN); FIN=1: out=LN fp32.
template <int FIN>
__global__ __launch_bounds__(256) void rln_kernel(
    const float* __restrict__ go, const float* __restrict__ xin,
    const float* __restrict__ g, const float* __restrict__ b,
    float* __restrict__ xout, __hip_bfloat16* __restrict__ sbout,
    float* __restrict__ out) {
  int row = blockIdx.x * 4 + (threadIdx.x >> 6);
  int lane = threadIdx.x & 63;
  const float* gr = go + (size_t)row * DD;
  const float* xr = xin + (size_t)row * DD;
  float v[4];
  float s = 0.f;
#pragma unroll
  for (int i = 0; i < 4; ++i) {
    int d = lane + 64 * i;
    v[i] = gr[d] + xr[d];
    s += v[i];
  }
#pragma unroll
  for (int off = 32; off; off >>= 1) s += __shfl_xor(s, off, 64);
  float mu = s * (1.f / DD);
  float vs = 0.f;
#pragma unroll
  for (int i = 0; i < 4; ++i) { float dd = v[i] - mu; vs = fmaf(dd, dd, vs); }
#pragma unroll
  for (int off = 32; off; off >>= 1) vs += __shfl_xor(vs, off, 64);
  float rr = rsqrtf(vs * (1.f / DD) + 1e-5f);
#pragma unroll
  for (int i = 0; i < 4; ++i) {
    int d = lane + 64 * i;
    float y = (v[i] - mu) * rr * g[d] + b[d];
    if (FIN) {
      out[(size_t)row * DD + d] = y;
    } else {
      xout[(size_t)row * DD + d] = v[i];
      sbout[(size_t)row * DD + d] = __float2bfloat16(y);
    }
  }
}

// ---------------- sliding-window attention, MFMA (R9/R11, unchanged) ----------------
__global__ __launch_bounds__(256) void attn_kernel(const __hip_bfloat16* __restrict__ qkv,
                                                   __hip_bfloat16* __restrict__ o) {
  __shared__ __align__(16) __hip_bfloat16 KsPs[128 * 72];
  __shared__ __align__(16) __hip_bfloat16 Vt[64 * 136];
  const int bh = blockIdx.y;
  const int b = bh >> 2, h = bh & 3;
  const int t0 = blockIdx.x * 64;
  const int sbase = t0 - 63;
  const int tid = threadIdx.x;

  const __hip_bfloat16* kb = qkv + (size_t)(b * TT) * 768 + 256 + h * 64;
  const __hip_bfloat16* vb = kb + 256;
  union U8 { uint4 u; __hip_bfloat16 hx[8]; };
#pragma unroll
  for (int it = 0; it < 4; ++it) {
    int f = tid + it * 256;
    int si = f >> 3;
    int c8 = f & 7;
    int s = sbase + si;
    U8 kr, vr;
    kr.u = make_uint4(0, 0, 0, 0); vr.u = make_uint4(0, 0, 0, 0);
    if (s >= 0 && s < TT) {
      kr.u = *(const uint4*)&kb[(size_t)s * 768 + 8 * c8];
      vr.u = *(const uint4*)&vb[(size_t)s * 768 + 8 * c8];
    }
    *(uint4*)&KsPs[si * 72 + c8 * 8] = kr.u;
    int pc = (si >> 3) ^ c8;
#pragma unroll
    for (int j = 0; j < 8; ++j) Vt[(c8 * 8 + j) * 136 + pc * 8 + (si & 7)] = vr.hx[j];
  }
  __syncthreads();

  const int wave = tid >> 6, lane = tid & 63;
  const int quad = lane >> 4, lr = lane & 15;

  const __hip_bfloat16* qrow = qkv + (size_t)(b * TT + t0 + wave * 16 + lr) * 768 + h * 64;
  bf16x8 qa0 = *(const bf16x8*)(qrow + quad * 8);
  bf16x8 qa1 = *(const bf16x8*)(qrow + 32 + quad * 8);
  f32x4 sc[8];
#pragma unroll
  for (int c = 0; c < 8; ++c) {
    f32x4 a = {};
    bf16x8 kf0 = *(const bf16x8*)&KsPs[(c * 16 + lr) * 72 + quad * 8];
    a = __builtin_amdgcn_mfma_f32_16x16x32_bf16(qa0, kf0, a, 0, 0, 0);
    bf16x8 kf1 = *(const bf16x8*)&KsPs[(c * 16 + lr) * 72 + 32 + quad * 8];
    a = __builtin_amdgcn_mfma_f32_16x16x32_bf16(qa1, kf1, a, 0, 0, 0);
    sc[c] = a;
  }
  __syncthreads();

#pragma unroll
  for (int reg = 0; reg < 4; ++reg) {
    int dt = wave * 16 + quad * 4 + reg;
    float pv[8];
    float mx = -1e30f;
#pragma unroll
    for (int c = 0; c < 8; ++c) {
      int si = c * 16 + lr;
      float v = sc[c][reg] * 0.125f;
      bool ok = (si >= dt) && (si <= dt + 63) && (sbase + si >= 0);
      v = ok ? v : -1e30f;
      pv[c] = v;
      mx = fmaxf(mx, v);
    }
#pragma unroll
    for (int off = 8; off; off >>= 1) mx = fmaxf(mx, __shfl_xor(mx, off, 64));
    float l = 0.f;
#pragma unroll
    for (int c = 0; c < 8; ++c) { float e = __expf(pv[c] - mx); pv[c] = e; l += e; }
#pragma unroll
    for (int off = 8; off; off >>= 1) l += __shfl_xor(l, off, 64);
    float rinv = 1.f / l;
#pragma unroll
    for (int c = 0; c < 8; ++c)
      KsPs[(wave * 16 + quad * 4 + reg) * 136 + c * 16 + lr] = __float2bfloat16(pv[c] * rinv);
  }

  __hip_bfloat16* obase = o + (size_t)(b * TT) * DD + h * 64;
#pragma unroll
  for (int ct = 0; ct < 4; ++ct) {
    f32x4 acc = {};
#pragma unroll
    for (int kk = 0; kk < 4; ++kk) {
      bf16x8 pa = *(const bf16x8*)&KsPs[(wave * 16 + lr) * 136 + kk * 32 + quad * 8];
      int dd = ct * 16 + lr;
      bf16x8 vf = *(const bf16x8*)&Vt[dd * 136 + (((kk * 4 + quad) ^ (dd >> 3)) * 8)];
      acc = __builtin_amdgcn_mfma_f32_16x16x32_bf16(pa, vf, acc, 0, 0, 0);
    }
#pragma unroll
    for (int reg = 0; reg < 4; ++reg) {
      int t = t0 + wave * 16 + quad * 4 + reg;
      obase[(size_t)t * DD + ct * 16 + lr] = __float2bfloat16(acc[reg]);
    }
  }
}

extern "C" void kernel_launch(void* const* d_in, const int* in_sizes, int n_in,
                              void* d_out, int out_size, void* d_ws, size_t ws_size,
                              hipStream_t stream) {
  const float* tokens = (const float*)d_in[0];
  const float* Wqkv = (const float*)d_in[1];
  const float* bqkv = (const float*)d_in[2];
  const float* Wo   = (const float*)d_in[3];
  const float* bo   = (const float*)d_in[4];
  const float* W1   = (const float*)d_in[5];
  const float* b1   = (const float*)d_in[6];
  const float* W2   = (const float*)d_in[7];
  const float* b2   = (const float*)d_in[8];
  const float* ln1g = (const float*)d_in[9];
  const float* ln1b = (const float*)d_in[10];
  const float* ln2g = (const float*)d_in[11];
  const float* ln2b = (const float*)d_in[12];
  const float* lnfg = (const float*)d_in[13];
  const float* lnfb = (const float*)d_in[14];
  float* out = (float*)d_out;

  const int M = BB * TT;                 // 8192
  const int ND = M * DD;

  float* x = (float*)d_ws;
  __hip_bfloat16* sb  = (__hip_bfloat16*)(x + ND);
  __hip_bfloat16* big = sb + (size_t)M * DD;
  __hip_bfloat16* wqb = big + (size_t)M * FF;
  __hip_bfloat16* wob = wqb + (size_t)NL * 3 * DD * DD;
  __hip_bfloat16* w1b = wob + (size_t)NL * DD * DD;
  __hip_bfloat16* w2b = w1b + (size_t)NL * FF * DD;
  float* gbuf = (float*)(w2b + (size_t)NL * DD * FF);   // W2 raw out, M*256 fp32

  prologue_kernel<<<3072 + M / 4, 256, 0, stream>>>(
      (const float4*)Wqkv, (const float4*)Wo, (const float4*)W1,
      (const float4*)W2, (ushort4*)wqb, tokens, ln1g, ln1b, x, sb);

  // layer-0 qkv
  mgemm_kernel<2, 4, 64, 256, 0, 0><<<dim3(6, 128), 256, 0, stream>>>(
      sb, wqb, bqkv, big, M, 768);

  for (int l = 0; l < NL; ++l) {
    attn_kernel<<<dim3(TT / 64, BB * 4), 256, 0, stream>>>(big, sb);
    // Wo + residual + ln2 (B small: streaming is cheap; keep fused)
    mgemm_ln_kernel<256><<<M / 32, 256, 0, stream>>>(
        sb, wob + (size_t)l * DD * DD, bo + l * DD, x,
        ln2g + l * DD, ln2b + l * DD, x, sb);
    // W1 + GELU: 64x128 tiles, grid (8,128)
    mgemm_kernel<2, 4, 64, 256, 1, 0><<<dim3(8, 128), 256, 0, stream>>>(
        sb, w1b + (size_t)l * FF * DD, b1 + l * FF, big, M, FF);
    // W2 plain: 64x64 tiles, grid (4,128), fp32 out
    mgemm_kernel<2, 2, 64, 1024, 0, 1><<<dim3(4, 128), 256, 0, stream>>>(
        big, w2b + (size_t)l * DD * FF, b2 + l * DD, gbuf, M, DD);
    if (l < NL - 1) {
      rln_kernel<0><<<M / 4, 256, 0, stream>>>(
          gbuf, x, ln1g + (l + 1) * DD, ln1b + (l + 1) * DD, x, sb, nullptr);
      mgemm_kernel<2, 4, 64, 256, 0, 0><<<dim3(6, 128), 256, 0, stream>>>(
          sb, wqb + (size_t)(l + 1) * 768 * DD, bqkv + (l + 1) * 768, big, M, 768);
    } else {
      rln_kernel<1><<<M / 4, 256, 0, stream>>>(
          gbuf, x, lnfg, lnfb, nullptr, nullptr, out);
    }
  }
}